// Round 2
// baseline (310.853 us; speedup 1.0000x reference)
//
#include <hip/hip_runtime.h>

#define B_ 8
#define L_ 2048
#define D_ 512
#define BI 64
#define BJ 32
#define JITERS (L_ / BJ)
#define KTILE (BJ * D_)          // 16384 f16 elements = 32 KB
#define VTILE (D_ * BJ)          // 16384 f16 elements = 32 KB
#define PSTRIDE 40

typedef __attribute__((ext_vector_type(4))) float  floatx4;
typedef __attribute__((ext_vector_type(8))) _Float16 halfx8;
typedef __attribute__((ext_vector_type(4))) int    intx4;

static __device__ __forceinline__ unsigned int f2h_bits(float x) {
  _Float16 h = (_Float16)x;
  return (unsigned int)__builtin_bit_cast(unsigned short, h);
}

static __device__ __forceinline__ void async_ld16(const unsigned short* g,
                                                  unsigned short* l) {
  __builtin_amdgcn_global_load_lds(
      (const __attribute__((address_space(1))) unsigned int*)g,
      (__attribute__((address_space(3))) unsigned int*)l, 16, 0, 0);
}

// ---------------------------------------------------------------------------
// prep: Kh[b][j][swizzled d-granules] = in*kw   (granule g stored at g^(j&7))
//       Vt[b][d][jt][swizzled j-granules] = in*vw (g stored at g^((d^(d>>2))&3))
// grid (L/64, D/64), 256 threads; kw/vw tile held in regs, b-loop inside.
// ---------------------------------------------------------------------------
__global__ __launch_bounds__(256) void prep(const float* __restrict__ in,
                                            const float* __restrict__ kw,
                                            const float* __restrict__ vw,
                                            unsigned short* __restrict__ Kh,
                                            unsigned short* __restrict__ Vt) {
  const int lt = blockIdx.x * 64;
  const int dt = blockIdx.y * 64;
  const int t  = threadIdx.x;
  __shared__ unsigned short vtile[64][66];

  float4 kwv[4], vwv[4];
  #pragma unroll
  for (int i = 0; i < 4; ++i) {
    int c = i * 256 + t, r = c >> 4, c4 = (c & 15) * 4;
    size_t wi = (size_t)(lt + r) * D_ + dt + c4;
    kwv[i] = *(const float4*)(kw + wi);
    vwv[i] = *(const float4*)(vw + wi);
  }

  for (int b = 0; b < B_; ++b) {
    #pragma unroll
    for (int i = 0; i < 4; ++i) {
      int c = i * 256 + t, r = c >> 4, c4 = (c & 15) * 4;
      int j = lt + r;
      size_t gi = ((size_t)b * L_ + j) * D_ + dt + c4;
      float4 iv = *(const float4*)(in + gi);
      unsigned int p0 = f2h_bits(iv.x * kwv[i].x) | (f2h_bits(iv.y * kwv[i].y) << 16);
      unsigned int p1 = f2h_bits(iv.z * kwv[i].z) | (f2h_bits(iv.w * kwv[i].w) << 16);
      int gs = (((dt + c4) >> 3) ^ (j & 7));
      uint2 pk; pk.x = p0; pk.y = p1;
      *(uint2*)(Kh + ((size_t)b * L_ + j) * D_ + gs * 8 + (c4 & 7)) = pk;
      vtile[r][c4 + 0] = (unsigned short)f2h_bits(iv.x * vwv[i].x);
      vtile[r][c4 + 1] = (unsigned short)f2h_bits(iv.y * vwv[i].y);
      vtile[r][c4 + 2] = (unsigned short)f2h_bits(iv.z * vwv[i].z);
      vtile[r][c4 + 3] = (unsigned short)f2h_bits(iv.w * vwv[i].w);
    }
    __syncthreads();
    #pragma unroll
    for (int i = 0; i < 2; ++i) {
      int c = i * 256 + t, dd = c >> 3, l8 = (c & 7) * 8;
      int dg = dt + dd;
      int jglob = lt + l8;
      int ov[4];
      #pragma unroll
      for (int k2 = 0; k2 < 4; ++k2)
        ov[k2] = (int)((unsigned int)vtile[l8 + 2 * k2][dd] |
                       ((unsigned int)vtile[l8 + 2 * k2 + 1][dd] << 16));
      int gv  = (jglob & 31) >> 3;
      int key = (dg ^ (dg >> 2)) & 3;
      size_t idx = (((size_t)b * D_ + dg) * (L_ / BJ) + (jglob >> 5)) * BJ +
                   (size_t)((gv ^ key) * 8);
      intx4 o; o[0] = ov[0]; o[1] = ov[1]; o[2] = ov[2]; o[3] = ov[3];
      *(intx4*)(Vt + idx) = o;
    }
    __syncthreads();
  }
}

// ---------------------------------------------------------------------------
// flash: grid (L/BI, B), 256 thr = 4 waves; wave owns a 16-row i-strip.
// Double-buffered async staging (global_load_lds), one barrier per j-tile.
// ---------------------------------------------------------------------------
static __device__ __forceinline__ void stage_tiles(const unsigned short* Kg,
                                                   const unsigned short* Vg,
                                                   unsigned short* Kl,
                                                   unsigned short* Vl, int tid) {
  const int wb = tid & 192;  // wave base (uniform per wave)
  #pragma unroll
  for (int i = 0; i < 8; ++i) {
    int gl = i * 256 + tid;
    async_ld16(Kg + (size_t)gl * 8, Kl + (i * 256 + wb) * 8);
  }
  #pragma unroll
  for (int i = 0; i < 8; ++i) {
    int gl = i * 256 + tid;
    int d = gl >> 2, g = gl & 3;
    async_ld16(Vg + (size_t)d * L_ + g * 8, Vl + (i * 256 + wb) * 8);
  }
}

__global__ __launch_bounds__(256, 1) void flash(const float* __restrict__ in,
                                                const float* __restrict__ qw,
                                                const unsigned short* __restrict__ Kh,
                                                const unsigned short* __restrict__ Vt,
                                                float* __restrict__ out) {
  const int b    = blockIdx.y;
  const int i0   = blockIdx.x * BI;
  const int tid  = threadIdx.x;
  const int w    = tid >> 6;
  const int lane = tid & 63;
  const int ln16 = lane & 15;
  const int quad = lane >> 4;

  __shared__ unsigned short Ksh[2 * KTILE];      // 64 KB
  __shared__ unsigned short Vsh[2 * VTILE];      // 64 KB
  __shared__ unsigned short Psh[BI * PSTRIDE];   //  5 KB

  const float kScale = 0.51012599f;  // log2(e)/sqrt(8): exp2-domain softmax

  // ---- Q fragments in registers (A-layout: m=ln16, k=quad*8+t) ----
  halfx8 qf[16];
  {
    const int qi = i0 + w * 16 + ln16;
    const float* ip = in + ((size_t)b * L_ + qi) * D_;
    const float* wp = qw + (size_t)qi * D_;
    #pragma unroll
    for (int ks = 0; ks < 16; ++ks) {
      int d0 = ks * 32 + quad * 8;
      float4 a0 = *(const float4*)(ip + d0);
      float4 a1 = *(const float4*)(ip + d0 + 4);
      float4 w0 = *(const float4*)(wp + d0);
      float4 w1 = *(const float4*)(wp + d0 + 4);
      halfx8 q;
      q[0] = (_Float16)(a0.x * w0.x * kScale);
      q[1] = (_Float16)(a0.y * w0.y * kScale);
      q[2] = (_Float16)(a0.z * w0.z * kScale);
      q[3] = (_Float16)(a0.w * w0.w * kScale);
      q[4] = (_Float16)(a1.x * w1.x * kScale);
      q[5] = (_Float16)(a1.y * w1.y * kScale);
      q[6] = (_Float16)(a1.z * w1.z * kScale);
      q[7] = (_Float16)(a1.w * w1.w * kScale);
      qf[ks] = q;
    }
  }

  float m_r[4], l_r[4];
  #pragma unroll
  for (int r = 0; r < 4; ++r) { m_r[r] = -1e30f; l_r[r] = 0.f; }
  floatx4 O[32];
  #pragma unroll
  for (int ct = 0; ct < 32; ++ct) O[ct] = (floatx4){0.f, 0.f, 0.f, 0.f};

  const unsigned short* KgB = Kh + (size_t)b * L_ * D_;
  const unsigned short* VgB = Vt + (size_t)b * D_ * L_;
  const int xk = ln16 & 7;
  const int xv = (ln16 ^ (ln16 >> 2)) & 3;

  // prologue: stage tile 0 into buffer 0
  stage_tiles(KgB, VgB, Ksh, Vsh, tid);

  for (int jb = 0; jb < JITERS; ++jb) {
    const int s = jb & 1;
    __syncthreads();  // drains vmcnt(0): buf[s] staged loads complete
    if (jb + 1 < JITERS)
      stage_tiles(KgB + (size_t)(jb + 1) * KTILE, VgB + (jb + 1) * BJ,
                  Ksh + (s ^ 1) * KTILE, Vsh + (s ^ 1) * VTILE, tid);

    const unsigned short* Kc = Ksh + s * KTILE;
    const unsigned short* Vc = Vsh + s * VTILE;

    // ---- S = Q K^T over this 32-j tile ----
    floatx4 sA[2];
    #pragma unroll
    for (int jt = 0; jt < 2; ++jt) {
      floatx4 acc = {0.f, 0.f, 0.f, 0.f};
      const unsigned short* kr = Kc + (size_t)(jt * 16 + ln16) * D_;
      #pragma unroll
      for (int ks = 0; ks < 16; ++ks) {
        halfx8 bk = *(const halfx8*)(kr + (((4 * ks + quad) ^ xk) * 8));
        acc = __builtin_amdgcn_mfma_f32_16x16x32_f16(qf[ks], bk, acc, 0, 0, 0);
      }
      sA[jt] = acc;
    }

    // ---- online softmax ----
    float mt[4];
    #pragma unroll
    for (int r = 0; r < 4; ++r) mt[r] = fmaxf(sA[0][r], sA[1][r]);
    #pragma unroll
    for (int off = 1; off < 16; off <<= 1) {
      #pragma unroll
      for (int r = 0; r < 4; ++r) mt[r] = fmaxf(mt[r], __shfl_xor(mt[r], off));
    }
    float al[4], ts[4];
    bool upd = false;
    #pragma unroll
    for (int r = 0; r < 4; ++r) {
      float mn = fmaxf(m_r[r], mt[r]);
      al[r] = exp2f(m_r[r] - mn);
      upd = upd || (mn != m_r[r]);
      m_r[r] = mn;
      float e0 = exp2f(sA[0][r] - mn);
      float e1 = exp2f(sA[1][r] - mn);
      sA[0][r] = e0; sA[1][r] = e1;
      ts[r] = e0 + e1;
    }
    #pragma unroll
    for (int off = 1; off < 16; off <<= 1) {
      #pragma unroll
      for (int r = 0; r < 4; ++r) ts[r] += __shfl_xor(ts[r], off);
    }
    #pragma unroll
    for (int r = 0; r < 4; ++r) l_r[r] = l_r[r] * al[r] + ts[r];

    if (__any((int)upd)) {
      #pragma unroll
      for (int ct = 0; ct < 32; ++ct) {
        #pragma unroll
        for (int r = 0; r < 4; ++r) O[ct][r] *= al[r];
      }
    }

    // ---- P: C-layout regs -> A-layout via LDS (same wave, no barrier) ----
    #pragma unroll
    for (int jt = 0; jt < 2; ++jt) {
      #pragma unroll
      for (int r = 0; r < 4; ++r)
        Psh[(w * 16 + quad * 4 + r) * PSTRIDE + jt * 16 + ln16] =
            (unsigned short)f2h_bits(sA[jt][r]);
    }
    halfx8 pf = *(const halfx8*)(&Psh[(w * 16 + ln16) * PSTRIDE + quad * 8]);

    // ---- O += P V ----
    const unsigned short* vb = Vc + ln16 * BJ + ((quad ^ xv) * 8);
    #pragma unroll
    for (int ct = 0; ct < 32; ++ct) {
      halfx8 vf = *(const halfx8*)(vb + ct * 16 * BJ);
      O[ct] = __builtin_amdgcn_mfma_f32_16x16x32_f16(pf, vf, O[ct], 0, 0, 0);
    }
  }

  // ---- epilogue ----
  float inv[4];
  #pragma unroll
  for (int r = 0; r < 4; ++r) inv[r] = 1.0f / l_r[r];
  float* op = out + ((size_t)b * L_ + i0 + w * 16 + quad * 4) * D_ + ln16;
  #pragma unroll
  for (int r = 0; r < 4; ++r) {
    #pragma unroll
    for (int ct = 0; ct < 32; ++ct)
      op[(size_t)r * D_ + ct * 16] = O[ct][r] * inv[r];
  }
}

// ---------------------------------------------------------------------------
extern "C" void kernel_launch(void* const* d_in, const int* in_sizes, int n_in,
                              void* d_out, int out_size, void* d_ws, size_t ws_size,
                              hipStream_t stream) {
  const float* in = (const float*)d_in[0];
  const float* qw = (const float*)d_in[1];
  const float* kw = (const float*)d_in[2];
  const float* vw = (const float*)d_in[3];
  float* out = (float*)d_out;

  unsigned short* Kh = (unsigned short*)d_ws;                 // 16.78 MB
  unsigned short* Vt = Kh + (size_t)B_ * L_ * D_;             // 16.78 MB

  prep<<<dim3(L_ / 64, D_ / 64), dim3(256), 0, stream>>>(in, kw, vw, Kh, Vt);
  flash<<<dim3(L_ / BI, B_), dim3(256), 0, stream>>>(in, qw, Kh, Vt, out);
}